// Round 14
// baseline (25.573 us; speedup 1.0000x reference)
//
#include <hip/hip_runtime.h>

// MosaicSDF: N=1024 points, G=512 grids, K=7 (343 nodes/grid).
// R14: grid-major two-kernel. R12/R13 taught: phase-2 is throughput-bound
// on per-pair row staging (67K pairs x 1.4KB = 92MB redundant traffic).
// Fix: block = (grid, 512-point half) -> the grid's row is staged into
// LDS ONCE and reused by all its active pairs.
//   K1 (1024 blocks x 256 thr): stage row (343 loads); sweep 512 points
//     (2 ballot rounds/wave) -> s_den[pl] for all, ballot-scan compact
//     (rx,ry,rz,gwr)+pid; phase B: 32 8-lane groups drain actives, R12's
//     exact per-pair math (slab=sub, static dy2/dz2, 49 nodes from the
//     SHARED row -> 8-addr broadcast reads, 3-step group reduce), plain
//     s_num[pid] stores (points unique per pair). Write coalesced float2
//     partial column P[g][nb..nb+512) = (num, den). Every entry written
//     -> no memset. No atomics. Deterministic.
//   K2 (256 blocks x 256 thr): point n = 4*bid+w; sum P[g][n] over g
//     (64 lanes x 8 rounds, butterfly), out = den>0 ? num/den : 0.

#define NPTS   1024
#define NGRIDS 512
#define PPITCH 1040            // float2 per grid column (1024 + 16 pad)
#define STEP   (1.0f / 6.0f)
#define FSQRT(x) __builtin_amdgcn_sqrtf(x)

__global__ __launch_bounds__(256) void msdf_part(
    const float* __restrict__ points,    // (N,3)
    const float* __restrict__ centers,   // (G,3)
    const float* __restrict__ scales,    // (G,)
    const float* __restrict__ vals,      // (G,343)
    float2* __restrict__ P)              // (G, PPITCH) partials (num,den)
{
    __shared__ float  s_row[344];
    __shared__ float4 s_pr[4][128];      // (rx,ry,rz,gwr) per active
    __shared__ unsigned short s_pid[4][128];
    __shared__ int   s_c[4];
    __shared__ float s_den[512];
    __shared__ float s_num[512];

    const int bid  = blockIdx.x;         // 0..1023
    const int g    = bid >> 1;           // grid id
    const int nb   = (bid & 1) << 9;     // point base: 0 or 512
    const int t    = threadIdx.x;
    const int w    = t >> 6;
    const int lane = t & 63;

    // Stage this grid's 343-float row once (reused by all active pairs).
    s_row[t] = vals[g * 343 + t];                    // t < 256 <= 343
    {
        const int u = t + 256;
        if (u < 343) s_row[u] = vals[g * 343 + u];
    }
    s_num[t] = 0.0f;
    s_num[t + 256] = 0.0f;

    const float cx   = centers[g * 3 + 0];           // block-uniform
    const float cy   = centers[g * 3 + 1];
    const float cz   = centers[g * 3 + 2];
    const float invs = 1.0f / scales[g];

    // ---- Phase A: sweep 512 points, write den, ballot-scan compact ----
    int cbase = 0;
    #pragma unroll
    for (int r = 0; r < 2; ++r) {
        const int pl = (r << 8) + (w << 6) + lane;   // local point 0..511
        const int n  = nb + pl;
        const float rx = (points[n * 3 + 0] - cx) * invs;
        const float ry = (points[n * 3 + 1] - cy) * invs;
        const float rz = (points[n * 3 + 2] - cz) * invs;
        const float gwr = 1.0f - FSQRT(rx * rx + ry * ry + rz * rz);
        const bool  act = (gwr > 0.0f);
        s_den[pl] = act ? gwr : 0.0f;
        const unsigned long long m = __ballot(act);
        if (act) {
            const int pos = cbase + (int)__popcll(m & ((1ull << lane) - 1ull));
            s_pr[w][pos]  = make_float4(rx, ry, rz, gwr);
            s_pid[w][pos] = (unsigned short)pl;
        }
        cbase += (int)__popcll(m);
    }
    if (lane == 0) s_c[w] = cbase;
    __syncthreads();

    const int o1 = s_c[0];
    const int o2 = o1 + s_c[1];
    const int o3 = o2 + s_c[2];
    const int C  = o3 + s_c[3];

    // ---- Phase B: 32 8-lane groups drain actives from the shared row ----
    const int grp = t >> 3;              // 0..31
    const int sub = t & 7;

    for (int a = grp; a < C; a += 32) {
        const int seg = (a >= o1) + (a >= o2) + (a >= o3);
        const int b0  = (seg == 0) ? 0 : (seg == 1) ? o1
                      : (seg == 2) ? o2 : o3;
        const float4 pr  = s_pr[seg][a - b0];
        const int    pid = (int)s_pid[seg][a - b0];

        float dy2[7], dz2[7];                        // static-indexed -> regs
        #pragma unroll
        for (int j = 0; j < 7; ++j) { const float d = pr.y - j * STEP; dy2[j] = d * d; }
        #pragma unroll
        for (int l = 0; l < 7; ++l) { const float d = pr.z - l * STEP; dz2[l] = d * d; }

        const int   slab = (sub < 7) ? sub : 6;
        const float dxv  = pr.x - slab * STEP;
        const float dx2  = (sub < 7) ? dxv * dxv : 4.0f;   // sub==7 -> wt 0
        const float* __restrict__ vrow = s_row + slab * 49;

        float ws = 0.0f, vs = 0.0f;
        #pragma unroll
        for (int j = 0; j < 7; ++j) {
            const float dxy = dx2 + dy2[j];
            #pragma unroll
            for (int l = 0; l < 7; ++l) {
                const float d2 = dxy + dz2[l];
                const float wt = (d2 <= 1.0f) ? FSQRT(d2) : 0.0f;
                ws += wt;
                vs  = fmaf(wt, vrow[j * 7 + l], vs);   // 8-addr broadcast
            }
        }
        #pragma unroll
        for (int o = 4; o >= 1; o >>= 1) {
            ws += __shfl_xor(ws, o);
            vs += __shfl_xor(vs, o);
        }
        if (sub == 0) {
            const float interp = (ws > 0.0f) ? (vs / ws) : 0.0f;
            s_num[pid] = interp * pr.w;              // pid unique per pair
        }
    }
    __syncthreads();

    // ---- Write coalesced partial column for this (grid, half) ----
    float2* __restrict__ Pg = P + (size_t)g * PPITCH + nb;
    Pg[t]       = make_float2(s_num[t],       s_den[t]);
    Pg[t + 256] = make_float2(s_num[t + 256], s_den[t + 256]);
}

__global__ __launch_bounds__(256) void msdf_reduce(
    const float2* __restrict__ P,        // (G, PPITCH)
    float* __restrict__ out)             // (N,)
{
    const int w    = threadIdx.x >> 6;
    const int lane = threadIdx.x & 63;
    const int n    = (blockIdx.x << 2) + w;          // 256 blocks x 4 points

    float num = 0.0f, den = 0.0f;
    #pragma unroll
    for (int k = 0; k < 8; ++k) {
        const int g = (k << 6) + lane;
        const float2 p = P[(size_t)g * PPITCH + n];
        num += p.x;
        den += p.y;
    }
    #pragma unroll
    for (int o = 32; o >= 1; o >>= 1) {
        num += __shfl_xor(num, o);
        den += __shfl_xor(den, o);
    }
    if (lane == 0) out[n] = (den > 0.0f) ? (num / den) : 0.0f;
}

extern "C" void kernel_launch(void* const* d_in, const int* in_sizes, int n_in,
                              void* d_out, int out_size, void* d_ws, size_t ws_size,
                              hipStream_t stream) {
    const float* points  = (const float*)d_in[0];   // (1024,3)
    const float* centers = (const float*)d_in[1];   // (512,3)
    const float* scales  = (const float*)d_in[2];   // (512,)
    const float* vals    = (const float*)d_in[3];   // (512,7,7,7)
    float* out = (float*)d_out;                     // (1024,)
    float2* P  = (float2*)d_ws;                     // 512*1040 float2 (4.3MB)

    msdf_part<<<1024, 256, 0, stream>>>(points, centers, scales, vals, P);
    msdf_reduce<<<256, 256, 0, stream>>>(P, out);
}